// Round 10
// baseline (418.950 us; speedup 1.0000x reference)
//
#include <hip/hip_runtime.h>

// Problem constants (from reference)
#define B_      128
#define NPIX    32      // N = M = 32
#define NNEO    30      // N-2
#define NCH     19      // state channels
#define LROWS   17      // staged pixel rows per block (15 cells + 2)
#define LPLANE  (LROWS * NPIX)   // 544 floats per LDS channel plane
#define OUTD    21      // OUT_DIM
#define ITERS   10
#define THRESHV 0.0007f

#define NCELLS      (B_ * NNEO * NNEO)   // 115,200
#define CLASS_ELEMS (NCELLS * 3)         // 345,600
#define HALOW       (NCH * NPIX)         // 608 floats per halo row

// ---------------------------------------------------------------------------
// R20 = R19 resubmission (R9's bench died at container level with no test
// output — protocol re-audited: residency OK (256 blocks all resident at
// 45.3KB LDS), flag monotonicity OK, double-buffer WAR OK, release/acquire
// visibility OK, no OOB, graph-capture-safe; attributing to infra flake).
// Structure: PERSISTENT KERNEL — state lives in LDS across all 10 steps.
//  - 256 blocks x 512 threads; block (b,g) owns cell rows [15g, 15g+15).
//  - One thread per cell; full 30/30/21 MLP in registers (static indexing).
//  - Per step, the two blocks sharing an image exchange ONE updated pixel
//    row (608 floats) via a double-buffered global slot + agent-scope
//    release/acquire flag handshake (strided loops: HALOW=608 > 512 threads,
//    R18's bug).
//  - perc is thread-private; no state staging, no launch drains.
// Numerics: accumulation order identical to all passing versions (bias;
// patches (pr,pc) asc: img row, ch rows 0..18; posx; posy; L2/L3 k asc).
// ---------------------------------------------------------------------------

#define ROW30(A, x, wrp) do { const float xx_ = (x); \
    const float* __restrict__ w_ = (wrp); \
    _Pragma("unroll") for (int o_ = 0; o_ < 30; o_++) (A)[o_] += xx_ * w_[o_]; \
} while (0)

#define ROW21(A, x, wrp) do { const float xx_ = (x); \
    const float* __restrict__ w_ = (wrp); \
    _Pragma("unroll") for (int o_ = 0; o_ < 21; o_++) (A)[o_] += xx_ * w_[o_]; \
} while (0)

__global__ void nca_zero_flags(int* __restrict__ flags) {
    if (threadIdx.x < 256) flags[threadIdx.x] = 0;
}

__global__ __launch_bounds__(512, 2)
void nca_persist(const float* __restrict__ img,
                 const float* __restrict__ W1, const float* __restrict__ b1,
                 const float* __restrict__ W2, const float* __restrict__ b2,
                 const float* __restrict__ W3, const float* __restrict__ b3,
                 float* __restrict__ hbuf, int* __restrict__ flags,
                 float* __restrict__ guesses_out, float* __restrict__ class_out)
{
    __shared__ float s_state[NCH * LPLANE];   // 41.3 KB, channel-planar
    __shared__ float s_img[NPIX * NPIX];      // 4 KB

    const int bid = blockIdx.x;
    const int b   = bid >> 1;                 // image index
    const int g   = bid & 1;                  // 0: cell rows 0-14, 1: 15-29
    const int c0  = g * 15;
    const int tid = threadIdx.x;

    // zero whole state tile (includes borders + halo rows)
    for (int t = tid; t < NCH * LPLANE; t += 512) s_state[t] = 0.0f;
    if (tid < 256)
        ((float4*)s_img)[tid] =
            ((const float4*)(img + (size_t)b * (NPIX * NPIX)))[tid];

    const bool active = tid < 15 * NNEO;      // 450 cells
    int r = 0, j = 0;
    if (active) { r = tid / NNEO; j = tid - r * NNEO; }
    const int i = c0 + r;                     // global cell row
    int px = i, py = j;                       // perc, thread-private

    // LDS row l <-> pixel row c0 + l. g=0 publishes pixel 15 (l=15),
    // receives pixel 16 (l=16); g=1 publishes pixel 16 (l=1), receives
    // pixel 15 (l=0).
    const int pub_lr = g ? 1 : 15;
    const int rcv_lr = g ? 0 : 16;
    float* __restrict__ myslot       = hbuf + (size_t)bid * (2 * HALOW);
    const float* __restrict__ pslot  = hbuf + (size_t)(bid ^ 1) * (2 * HALOW);
    int* pflag = flags + (bid ^ 1);

    __syncthreads();

    for (int t = 0; t < ITERS; t++) {
        // ---- receive partner's halo row (updated at step t-1) -------------
        if (t > 0) {
            if (tid == 0) {
                while (__hip_atomic_load(pflag, __ATOMIC_ACQUIRE,
                                         __HIP_MEMORY_SCOPE_AGENT) < t)
                    __builtin_amdgcn_s_sleep(16);
            }
            __syncthreads();
            for (int t2 = tid; t2 < HALOW; t2 += 512) {
                const int ch = t2 >> 5, x = t2 & 31;
                s_state[ch * LPLANE + rcv_lr * NPIX + x] =
                    pslot[((t - 1) & 1) * HALOW + t2];
            }
            __syncthreads();
        }

        // ---- MLP (all 30/30/21 outputs per thread, registers only) --------
        float ov[21];
        if (active) {
            float acc[30];
#pragma unroll
            for (int o = 0; o < 30; o++) acc[o] = b1[o];
            if (t == 0) {
                // state == 0: only image rows contribute (bit-exact skip)
#pragma clang loop unroll(disable)
                for (int pr = 0; pr < 3; pr++) {
#pragma clang loop unroll(disable)
                    for (int pc = 0; pc < 3; pc++) {
                        const float iv = s_img[(px + pr) * NPIX + (py + pc)];
                        ROW30(acc, iv, W1 + (pr * 3 + pc) * 600);
                    }
                }
            } else {
#pragma clang loop unroll(disable)
                for (int pr = 0; pr < 3; pr++) {
#pragma clang loop unroll(disable)
                    for (int pc = 0; pc < 3; pc++) {
                        const float iv = s_img[(px + pr) * NPIX + (py + pc)];
                        const float* __restrict__ wp =
                            W1 + (pr * 3 + pc) * 600;
                        const int sb = (r + pr) * NPIX + (j + pc);
                        float fv[NCH];
#pragma unroll
                        for (int ch = 0; ch < NCH; ch++)
                            fv[ch] = s_state[ch * LPLANE + sb];
                        ROW30(acc, iv, wp);          // row 0: image
#pragma unroll
                        for (int ch = 0; ch < NCH; ch++)
                            ROW30(acc, fv[ch], wp + (ch + 1) * 30);
                    }
                }
            }
            const float posx = (float)(px - 16) * 0.0625f;
            const float posy = (float)(py - 16) * 0.0625f;
            ROW30(acc, posx, W1 + 180 * 30);
            ROW30(acc, posy, W1 + 181 * 30);

            float a1[30];
#pragma unroll
            for (int o = 0; o < 30; o++) a1[o] = fmaxf(acc[o], 0.0f);

            float h2[30];
#pragma unroll
            for (int o = 0; o < 30; o++) h2[o] = b2[o];
#pragma unroll
            for (int k = 0; k < 30; k++)
                ROW30(h2, a1[k], W2 + k * 30);
#pragma unroll
            for (int o = 0; o < 30; o++) h2[o] = fmaxf(h2[o], 0.0f);

#pragma unroll
            for (int c = 0; c < 21; c++) ov[c] = b3[c];
#pragma unroll
            for (int k = 0; k < 30; k++)
                ROW21(ov, h2[k], W3 + k * 21);
        }

        __syncthreads();                      // all state reads done

        if (t < ITERS - 1) {
            // ---- state update + movement (thread-exclusive center) --------
            if (active) {
                const int cen = (r + 1) * NPIX + (j + 1);
#pragma unroll
                for (int ch = 0; ch < NCH; ch++)
                    s_state[ch * LPLANE + cen] += ov[ch];
                int dxm = (ov[19] > THRESHV) ? 1 : ((ov[19] < -THRESHV) ? -1 : 0);
                int dym = (ov[20] > THRESHV) ? 1 : ((ov[20] < -THRESHV) ? -1 : 0);
                px += dxm; py += dym;
                px = (px < 0) ? 0 : ((px > NNEO - 1) ? NNEO - 1 : px);
                py = (py < 0) ? 0 : ((py > NNEO - 1) ? NNEO - 1 : py);
            }
            __syncthreads();                  // updates visible in LDS
            // ---- publish boundary row ------------------------------------
            for (int t2 = tid; t2 < HALOW; t2 += 512) {
                myslot[(t & 1) * HALOW + t2] =
                    s_state[(t2 >> 5) * LPLANE + pub_lr * NPIX + (t2 & 31)];
            }
            __syncthreads();                  // vmcnt(0) drain: stores in L2
            if (tid == 0)
                __hip_atomic_store(flags + bid, t + 1, __ATOMIC_RELEASE,
                                   __HIP_MEMORY_SCOPE_AGENT);
        } else if (active) {
            // ---- final outputs -------------------------------------------
            const int gcell = (b * NNEO + i) * NNEO + j;
            float* __restrict__ gout = guesses_out + (size_t)gcell * OUTD;
#pragma unroll
            for (int c = 0; c < 21; c++) gout[c] = ov[c];
            const int cen = (r + 1) * NPIX + (j + 1);
            float* __restrict__ cs = class_out + (size_t)gcell * 3;
#pragma unroll
            for (int cc = 0; cc < 3; cc++)
                cs[cc] = s_state[(16 + cc) * LPLANE + cen] + ov[16 + cc];
        }
    }
}

extern "C" void kernel_launch(void* const* d_in, const int* in_sizes, int n_in,
                              void* d_out, int out_size, void* d_ws, size_t ws_size,
                              hipStream_t stream) {
    const float* img = (const float*)d_in[0];
    const float* W1  = (const float*)d_in[1];
    const float* b1  = (const float*)d_in[2];
    const float* W2  = (const float*)d_in[3];
    const float* b2  = (const float*)d_in[4];
    const float* W3  = (const float*)d_in[5];
    const float* b3  = (const float*)d_in[6];

    float* out = (float*)d_out;
    float* class_out   = out;                 // 345,600 floats
    float* guesses_out = out + CLASS_ELEMS;   // 2,419,200 floats

    float* hbuf  = (float*)d_ws;              // 256 blocks x 2 slots x 608
    int*   flags = (int*)(hbuf + 256 * 2 * HALOW);

    nca_zero_flags<<<1, 256, 0, stream>>>(flags);

    nca_persist<<<256, 512, 0, stream>>>(img, W1, b1, W2, b2, W3, b3,
                                         hbuf, flags,
                                         guesses_out, class_out);
}